// Round 1
// baseline (1019.279 us; speedup 1.0000x reference)
//
#include <hip/hip_runtime.h>
#include <math.h>

#define NB 8
#define NT 32
#define NAG 50
#define MTASK 100
#define MTOP 10
#define NNB 10
#define LDIM 5
#define HDIM 512
#define INDIM 1610          // 500 + 1000 + 10 + 100
#define NROWS (NB*NT*NAG)   // 12800
#define NOUT (MTOP+1)       // 11

// ---------------- Kernel 1: total_beta + top-10 tasks ----------------
__global__ void k_totalbeta_topk(const float* __restrict__ beta,
                                 float* __restrict__ total_beta,
                                 int* __restrict__ tasks) {
    int row = blockIdx.x;  // (b*T+t)*NAG + agent
    __shared__ float tb[MTASK];
    int m = threadIdx.x;
    if (m < MTASK) {
        const float* bp = beta + ((size_t)row * MTASK + m) * LDIM;
        float s = bp[0] + bp[1] + bp[2] + bp[3] + bp[4];
        tb[m] = s;
        total_beta[(size_t)row * MTASK + m] = s;
    }
    __syncthreads();
    if (threadIdx.x == 0) {
        // stable top-k: strict '>' keeps the lowest index on ties (lax.top_k semantics)
        for (int k = 0; k < MTOP; ++k) {
            float best = -INFINITY; int bi = 0;
            for (int mm = 0; mm < MTASK; ++mm) {
                float v = tb[mm];
                if (v > best) { best = v; bi = mm; }
            }
            tasks[row * MTOP + k] = bi;
            tb[bi] = -INFINITY;
        }
    }
}

// ---------------- Kernel 2: neighbor selection ----------------
__global__ void k_neighbors(const float* __restrict__ total_beta,
                            const int* __restrict__ tasks,
                            int* __restrict__ neighbors) {
    int row = blockIdx.x;        // bt*NAG + i
    int bt = row / NAG;
    int i  = row - bt * NAG;
    __shared__ int tk[MTOP];
    __shared__ float bestv[NAG];
    if (threadIdx.x < MTOP) tk[threadIdx.x] = tasks[row * MTOP + threadIdx.x];
    __syncthreads();
    int a = threadIdx.x;
    if (a < NAG) {
        const float* tba = total_beta + ((size_t)bt * NAG + a) * MTASK;
        float mx = -INFINITY;
        #pragma unroll
        for (int k = 0; k < MTOP; ++k) mx = fmaxf(mx, tba[tk[k]]);
        bestv[a] = (a == i) ? -INFINITY : mx;
    }
    __syncthreads();
    if (threadIdx.x == 0) {
        for (int k = 0; k < NNB; ++k) {
            float best = -INFINITY; int bi = 0;
            for (int a2 = 0; a2 < NAG; ++a2) {
                float v = bestv[a2];
                if (v > best) { best = v; bi = a2; }
            }
            neighbors[row * NNB + k] = bi;
            bestv[bi] = -INFINITY;
        }
    }
}

// ---------------- Kernel 3: build 1610-dim inputs ----------------
__global__ void k_build_inputs(const float* __restrict__ beta,
                               const float* __restrict__ actions,
                               const float* __restrict__ power,
                               const int* __restrict__ prev,
                               const int* __restrict__ tasks,
                               const int* __restrict__ neighbors,
                               float* __restrict__ inputs) {
    int row = blockIdx.x;  // bt*NAG + i
    int bt = row / NAG;
    __shared__ int tk[MTOP], nb[NNB], pa[NNB];
    __shared__ float pw[NNB];
    if (threadIdx.x < MTOP) tk[threadIdx.x] = tasks[row * MTOP + threadIdx.x];
    if (threadIdx.x >= 32 && threadIdx.x < 32 + NNB) {
        int j = threadIdx.x - 32;
        int nbj = neighbors[row * NNB + j];
        nb[j] = nbj;
        pa[j] = prev[bt * NAG + nbj];
        pw[j] = power[bt * NAG + nbj];
    }
    __syncthreads();
    float* out = inputs + (size_t)row * INDIM;
    // beta_feat: 500, order (k, j, l)
    for (int idx = threadIdx.x; idx < MTOP * NNB * LDIM; idx += blockDim.x) {
        int k = idx / (NNB * LDIM);
        int r = idx - k * (NNB * LDIM);
        int j = r / LDIM;
        int l = r - j * LDIM;
        out[idx] = beta[(((size_t)bt * NAG + nb[j]) * MTASK + tk[k]) * LDIM + l];
    }
    // act_feat: 1000, order (j, m)
    for (int idx = threadIdx.x; idx < NNB * MTASK; idx += blockDim.x) {
        int j = idx / MTASK;
        int m = idx - j * MTASK;
        out[500 + idx] = actions[((size_t)bt * NAG + nb[j]) * MTASK + m];
    }
    // pow_feat: 10
    if (threadIdx.x < NNB) out[1500 + threadIdx.x] = pw[threadIdx.x];
    // prev_feat: 100, order (k, j)
    for (int idx = threadIdx.x; idx < MTOP * NNB; idx += blockDim.x) {
        int k = idx / NNB;
        int j = idx - k * NNB;
        out[1510 + idx] = (tk[k] == pa[j]) ? 1.0f : 0.0f;
    }
}

// ---------------- Tiled fp32 GEMM: C = act(A[M,K] @ W[K,N] + b) ----------------
template<bool RELU>
__global__ void k_gemm(const float* __restrict__ A, const float* __restrict__ W,
                       const float* __restrict__ bias, float* __restrict__ C,
                       int M, int N, int K) {
    const int BK = 16;
    __shared__ float As[BK][64 + 1];  // As[k][m]
    __shared__ float Bs[BK][64 + 1];  // Bs[k][n]
    int m0 = blockIdx.x * 64;
    int n0 = blockIdx.y * 64;
    int tid = threadIdx.x;
    int tx = tid & 15, ty = tid >> 4;
    float acc[4][4] = {};
    for (int kt = 0; kt < K; kt += BK) {
        // A tile 64 x BK
        #pragma unroll
        for (int e = tid; e < 64 * BK; e += 256) {
            int ar = e >> 4;
            int ak = e & 15;
            int gk = kt + ak;
            As[ak][ar] = (gk < K) ? A[(size_t)(m0 + ar) * K + gk] : 0.f;
        }
        // B tile BK x 64
        #pragma unroll
        for (int e = tid; e < BK * 64; e += 256) {
            int br = e >> 6;
            int bn = e & 63;
            int gk = kt + br;
            Bs[br][bn] = (gk < K) ? W[(size_t)gk * N + n0 + bn] : 0.f;
        }
        __syncthreads();
        #pragma unroll
        for (int kk = 0; kk < BK; ++kk) {
            float a[4], b[4];
            #pragma unroll
            for (int i = 0; i < 4; ++i) a[i] = As[kk][ty * 4 + i];
            #pragma unroll
            for (int j = 0; j < 4; ++j) b[j] = Bs[kk][tx * 4 + j];
            #pragma unroll
            for (int i = 0; i < 4; ++i)
                #pragma unroll
                for (int j = 0; j < 4; ++j)
                    acc[i][j] += a[i] * b[j];
        }
        __syncthreads();
    }
    #pragma unroll
    for (int i = 0; i < 4; ++i) {
        int mm = m0 + ty * 4 + i;
        #pragma unroll
        for (int j = 0; j < 4; ++j) {
            int nn = n0 + tx * 4 + j;
            float c = acc[i][j] + bias[nn];
            if (RELU) c = fmaxf(c, 0.f);
            C[(size_t)mm * N + nn] = c;
        }
    }
}

// ---------------- GEMM3: N=11, one thread per output ----------------
__global__ void k_gemm3(const float* __restrict__ h2, const float* __restrict__ W3,
                        const float* __restrict__ b3, float* __restrict__ out) {
    int idx = blockIdx.x * blockDim.x + threadIdx.x;
    if (idx >= NROWS * NOUT) return;
    int row = idx / NOUT;
    int n = idx - row * NOUT;
    const float* hp = h2 + (size_t)row * HDIM;
    float s = b3[n];
    #pragma unroll 8
    for (int k = 0; k < HDIM; ++k) s += hp[k] * W3[k * NOUT + n];
    out[idx] = s;
}

extern "C" void kernel_launch(void* const* d_in, const int* in_sizes, int n_in,
                              void* d_out, int out_size, void* d_ws, size_t ws_size,
                              hipStream_t stream) {
    const float* beta    = (const float*)d_in[0];
    const float* actions = (const float*)d_in[1];
    const float* power   = (const float*)d_in[2];
    const int*   prev    = (const int*)d_in[3];
    const float* W1      = (const float*)d_in[4];
    const float* b1      = (const float*)d_in[5];
    const float* W2      = (const float*)d_in[6];
    const float* b2      = (const float*)d_in[7];
    const float* W3      = (const float*)d_in[8];
    const float* b3      = (const float*)d_in[9];
    float* out = (float*)d_out;

    char* ws = (char*)d_ws;
    size_t off = 0;
    float* total_beta = (float*)(ws + off); off += (size_t)NROWS * MTASK * 4;   // 5.12 MB
    int*   tasks      = (int*)  (ws + off); off += (size_t)NROWS * MTOP * 4;    // 0.51 MB
    int*   neighbors  = (int*)  (ws + off); off += (size_t)NROWS * NNB * 4;     // 0.51 MB
    float* inputs     = (float*)(ws + off); off += (size_t)NROWS * INDIM * 4;   // 82.4 MB
    float* h1         = (float*)(ws + off); off += (size_t)NROWS * HDIM * 4;    // 26.2 MB
    float* h2         = (float*)(ws + off); off += (size_t)NROWS * HDIM * 4;    // 26.2 MB

    k_totalbeta_topk<<<NROWS, 128, 0, stream>>>(beta, total_beta, tasks);
    k_neighbors<<<NROWS, 64, 0, stream>>>(total_beta, tasks, neighbors);
    k_build_inputs<<<NROWS, 256, 0, stream>>>(beta, actions, power, prev, tasks,
                                              neighbors, inputs);
    dim3 g1(NROWS / 64, HDIM / 64);
    k_gemm<true><<<g1, 256, 0, stream>>>(inputs, W1, b1, h1, NROWS, HDIM, INDIM);
    dim3 g2(NROWS / 64, HDIM / 64);
    k_gemm<true><<<g2, 256, 0, stream>>>(h1, W2, b2, h2, NROWS, HDIM, HDIM);
    int n3 = NROWS * NOUT;
    k_gemm3<<<(n3 + 255) / 256, 256, 0, stream>>>(h2, W3, b3, out);
}

// Round 2
// 433.998 us; speedup vs baseline: 2.3486x; 2.3486x over previous
//
#include <hip/hip_runtime.h>
#include <math.h>

#define NB 8
#define NT 32
#define NAG 50
#define MTASK 100
#define MTOP 10
#define NNB 10
#define LDIM 5
#define HDIM 512
#define INDIM 1610
#define KP1 1632            // INDIM padded to multiple of 32 (16B-aligned rows)
#define NROWS (NB*NT*NAG)   // 12800
#define NOUT (MTOP+1)       // 11

typedef float f32x4 __attribute__((ext_vector_type(4)));
typedef __bf16 bf16x8 __attribute__((ext_vector_type(8)));

// ---------------- Kernel 1: total_beta + top-10 tasks ----------------
__global__ void k_totalbeta_topk(const float* __restrict__ beta,
                                 float* __restrict__ total_beta,
                                 int* __restrict__ tasks) {
    int row = blockIdx.x;
    __shared__ float tb[MTASK];
    int m = threadIdx.x;
    if (m < MTASK) {
        const float* bp = beta + ((size_t)row * MTASK + m) * LDIM;
        float s = bp[0] + bp[1] + bp[2] + bp[3] + bp[4];
        tb[m] = s;
        total_beta[(size_t)row * MTASK + m] = s;
    }
    __syncthreads();
    if (threadIdx.x == 0) {
        for (int k = 0; k < MTOP; ++k) {
            float best = -INFINITY; int bi = 0;
            for (int mm = 0; mm < MTASK; ++mm) {
                float v = tb[mm];
                if (v > best) { best = v; bi = mm; }
            }
            tasks[row * MTOP + k] = bi;
            tb[bi] = -INFINITY;
        }
    }
}

// ---------------- Kernel 2: neighbor selection ----------------
__global__ void k_neighbors(const float* __restrict__ total_beta,
                            const int* __restrict__ tasks,
                            int* __restrict__ neighbors) {
    int row = blockIdx.x;
    int bt = row / NAG;
    int i  = row - bt * NAG;
    __shared__ int tk[MTOP];
    __shared__ float bestv[NAG];
    if (threadIdx.x < MTOP) tk[threadIdx.x] = tasks[row * MTOP + threadIdx.x];
    __syncthreads();
    int a = threadIdx.x;
    if (a < NAG) {
        const float* tba = total_beta + ((size_t)bt * NAG + a) * MTASK;
        float mx = -INFINITY;
        #pragma unroll
        for (int k = 0; k < MTOP; ++k) mx = fmaxf(mx, tba[tk[k]]);
        bestv[a] = (a == i) ? -INFINITY : mx;
    }
    __syncthreads();
    if (threadIdx.x == 0) {
        for (int k = 0; k < NNB; ++k) {
            float best = -INFINITY; int bi = 0;
            for (int a2 = 0; a2 < NAG; ++a2) {
                float v = bestv[a2];
                if (v > best) { best = v; bi = a2; }
            }
            neighbors[row * NNB + k] = bi;
            bestv[bi] = -INFINITY;
        }
    }
}

// ---------------- Kernel 3: build 1610-dim inputs as split bf16 ----------------
__global__ void k_build_inputs(const float* __restrict__ beta,
                               const float* __restrict__ actions,
                               const float* __restrict__ power,
                               const int* __restrict__ prev,
                               const int* __restrict__ tasks,
                               const int* __restrict__ neighbors,
                               __bf16* __restrict__ Ah, __bf16* __restrict__ Al) {
    int row = blockIdx.x;
    int bt = row / NAG;
    __shared__ int tk[MTOP], nb[NNB], pa[NNB];
    __shared__ float pw[NNB];
    if (threadIdx.x < MTOP) tk[threadIdx.x] = tasks[row * MTOP + threadIdx.x];
    if (threadIdx.x >= 32 && threadIdx.x < 32 + NNB) {
        int j = threadIdx.x - 32;
        int nbj = neighbors[row * NNB + j];
        nb[j] = nbj;
        pa[j] = prev[bt * NAG + nbj];
        pw[j] = power[bt * NAG + nbj];
    }
    __syncthreads();
    __bf16* oh = Ah + (size_t)row * KP1;
    __bf16* ol = Al + (size_t)row * KP1;
    for (int idx = threadIdx.x; idx < KP1; idx += blockDim.x) {
        float f = 0.f;
        if (idx < 500) {
            int k = idx / (NNB * LDIM);
            int r = idx - k * (NNB * LDIM);
            int j = r / LDIM;
            int l = r - j * LDIM;
            f = beta[(((size_t)bt * NAG + nb[j]) * MTASK + tk[k]) * LDIM + l];
        } else if (idx < 1500) {
            int i2 = idx - 500;
            int j = i2 / MTASK;
            int m = i2 - j * MTASK;
            f = actions[((size_t)bt * NAG + nb[j]) * MTASK + m];
        } else if (idx < 1510) {
            f = pw[idx - 1500];
        } else if (idx < 1610) {
            int i2 = idx - 1510;
            int k = i2 / NNB;
            int j = i2 - k * NNB;
            f = (tk[k] == pa[j]) ? 1.0f : 0.0f;
        }
        __bf16 h = (__bf16)f;
        __bf16 lo = (__bf16)(f - (float)h);
        oh[idx] = h;
        ol[idx] = lo;
    }
}

// ---------------- Weight prep: W[K][N] -> Wt hi/lo [N][KP] ----------------
__global__ void k_prep_w(const float* __restrict__ W,
                         __bf16* __restrict__ Th, __bf16* __restrict__ Tl,
                         int K, int N, int KP) {
    int idx = blockIdx.x * blockDim.x + threadIdx.x;
    if (idx >= N * KP) return;
    int n = idx / KP, kp = idx - n * KP;
    float f = (kp < K) ? W[(size_t)kp * N + n] : 0.f;
    __bf16 h = (__bf16)f;
    __bf16 l = (__bf16)(f - (float)h);
    Th[idx] = h;
    Tl[idx] = l;
}

// ---------------- split-bf16 MFMA GEMM ----------------
// C[M][Nout] = relu(A[M][KP] @ Bt[Nout][KP]^T + bias), A,Bt given as hi/lo split.
// 3 passes: Ah*Bh + Al*Bh + Ah*Bl. 128x128 tile, 4 waves (2x2), 16x16x32 MFMA.
__device__ __forceinline__ void gload16(const __bf16* g, __bf16* l) {
    __builtin_amdgcn_global_load_lds(
        (__attribute__((address_space(1))) void*)(g),
        (__attribute__((address_space(3))) void*)(l), 16, 0, 0);
}

template<int KP, bool SPLIT_OUT>
__global__ __launch_bounds__(256, 2) void k_mfma_gemm(
    const __bf16* __restrict__ Ah, const __bf16* __restrict__ Al,
    const __bf16* __restrict__ Bh, const __bf16* __restrict__ Bl,
    const float* __restrict__ bias,
    __bf16* __restrict__ Ch, __bf16* __restrict__ Cl,
    float* __restrict__ Cf, int Nout) {
    constexpr int NK = KP / 32;
    constexpr int NK3 = NK * 3;
    // K-chunk-major LDS: [buf][kc(4)][row(128)][8 bf16] -> 8KB per buf per operand
    __shared__ __align__(16) __bf16 sA[2][4096];
    __shared__ __align__(16) __bf16 sB[2][4096];
    int tid = threadIdx.x, wid = tid >> 6, lane = tid & 63;
    int m0 = blockIdx.x * 128, n0 = blockIdx.y * 128;
    int q1 = wid * 64 + lane, q2 = q1 + 256;
    int ar1 = q1 & 127, ac1 = q1 >> 7;
    int ar2 = q2 & 127, ac2 = q2 >> 7;

    auto stage = [&](int kt3, int buf) {
        int p = kt3 / NK, kk = kt3 - p * NK;
        const __bf16* ga = ((p == 1) ? Al : Ah) + (size_t)m0 * KP + kk * 32;
        const __bf16* gb = ((p == 2) ? Bl : Bh) + (size_t)n0 * KP + kk * 32;
        gload16(ga + (size_t)ar1 * KP + ac1 * 8, &sA[buf][(wid * 64) * 8]);
        gload16(ga + (size_t)ar2 * KP + ac2 * 8, &sA[buf][(256 + wid * 64) * 8]);
        gload16(gb + (size_t)ar1 * KP + ac1 * 8, &sB[buf][(wid * 64) * 8]);
        gload16(gb + (size_t)ar2 * KP + ac2 * 8, &sB[buf][(256 + wid * 64) * 8]);
    };

    int wr = wid >> 1, wc = wid & 1;
    int lrow = lane & 15, lk = lane >> 4;
    int aoff = (lk * 128 + wr * 64 + lrow) * 8;
    int boff = (lk * 128 + wc * 64 + lrow) * 8;
    f32x4 acc[4][4] = {};

    stage(0, 0);
    for (int kt = 0; kt < NK3; ++kt) {
        int buf = kt & 1;
        __syncthreads();                    // staged tile ready; prior reads drained
        if (kt + 1 < NK3) stage(kt + 1, buf ^ 1);
        bf16x8 af[4], bfr[4];
        #pragma unroll
        for (int i = 0; i < 4; ++i) af[i] = *(const bf16x8*)&sA[buf][aoff + i * 16 * 8];
        #pragma unroll
        for (int j = 0; j < 4; ++j) bfr[j] = *(const bf16x8*)&sB[buf][boff + j * 16 * 8];
        #pragma unroll
        for (int i = 0; i < 4; ++i)
            #pragma unroll
            for (int j = 0; j < 4; ++j)
                acc[i][j] = __builtin_amdgcn_mfma_f32_16x16x32_bf16(af[i], bfr[j], acc[i][j], 0, 0, 0);
    }

    // epilogue: D row = (lane>>4)*4 + reg, col = lane&15  [verified layout]
    #pragma unroll
    for (int i = 0; i < 4; ++i) {
        int mbase = m0 + wr * 64 + i * 16 + lk * 4;
        #pragma unroll
        for (int j = 0; j < 4; ++j) {
            int n = n0 + wc * 64 + j * 16 + lrow;
            float bv = bias[n];
            #pragma unroll
            for (int r2 = 0; r2 < 4; ++r2) {
                float c = fmaxf(acc[i][j][r2] + bv, 0.f);
                size_t off = (size_t)(mbase + r2) * Nout + n;
                if (SPLIT_OUT) {
                    __bf16 h = (__bf16)c;
                    Ch[off] = h;
                    Cl[off] = (__bf16)(c - (float)h);
                } else {
                    Cf[off] = c;
                }
            }
        }
    }
}

// ---------------- GEMM3: N=11, fp32 ----------------
__global__ void k_gemm3(const float* __restrict__ h2, const float* __restrict__ W3,
                        const float* __restrict__ b3, float* __restrict__ out) {
    int idx = blockIdx.x * blockDim.x + threadIdx.x;
    if (idx >= NROWS * NOUT) return;
    int row = idx / NOUT;
    int n = idx - row * NOUT;
    const float* hp = h2 + (size_t)row * HDIM;
    float s = b3[n];
    #pragma unroll 8
    for (int k = 0; k < HDIM; ++k) s += hp[k] * W3[k * NOUT + n];
    out[idx] = s;
}

extern "C" void kernel_launch(void* const* d_in, const int* in_sizes, int n_in,
                              void* d_out, int out_size, void* d_ws, size_t ws_size,
                              hipStream_t stream) {
    const float* beta    = (const float*)d_in[0];
    const float* actions = (const float*)d_in[1];
    const float* power   = (const float*)d_in[2];
    const int*   prev    = (const int*)d_in[3];
    const float* W1      = (const float*)d_in[4];
    const float* b1      = (const float*)d_in[5];
    const float* W2      = (const float*)d_in[6];
    const float* b2      = (const float*)d_in[7];
    const float* W3      = (const float*)d_in[8];
    const float* b3      = (const float*)d_in[9];
    float* out = (float*)d_out;

    char* ws = (char*)d_ws;
    size_t off = 0;
    auto alloc = [&](size_t bytes) { void* p = ws + off; off += (bytes + 255) & ~(size_t)255; return p; };
    float*  total_beta = (float*) alloc((size_t)NROWS * MTASK * 4);
    int*    tasks      = (int*)   alloc((size_t)NROWS * MTOP * 4);
    int*    neighbors  = (int*)   alloc((size_t)NROWS * NNB * 4);
    __bf16* Ah         = (__bf16*)alloc((size_t)NROWS * KP1 * 2);
    __bf16* Al         = (__bf16*)alloc((size_t)NROWS * KP1 * 2);
    __bf16* W1th       = (__bf16*)alloc((size_t)HDIM * KP1 * 2);
    __bf16* W1tl       = (__bf16*)alloc((size_t)HDIM * KP1 * 2);
    __bf16* W2th       = (__bf16*)alloc((size_t)HDIM * HDIM * 2);
    __bf16* W2tl       = (__bf16*)alloc((size_t)HDIM * HDIM * 2);
    __bf16* h1h        = (__bf16*)alloc((size_t)NROWS * HDIM * 2);
    __bf16* h1l        = (__bf16*)alloc((size_t)NROWS * HDIM * 2);
    float*  h2         = (float*) alloc((size_t)NROWS * HDIM * 4);

    k_totalbeta_topk<<<NROWS, 128, 0, stream>>>(beta, total_beta, tasks);
    k_neighbors<<<NROWS, 64, 0, stream>>>(total_beta, tasks, neighbors);
    k_build_inputs<<<NROWS, 256, 0, stream>>>(beta, actions, power, prev, tasks,
                                              neighbors, Ah, Al);
    {
        int n1 = HDIM * KP1;
        k_prep_w<<<(n1 + 255) / 256, 256, 0, stream>>>(W1, W1th, W1tl, INDIM, HDIM, KP1);
        int n2 = HDIM * HDIM;
        k_prep_w<<<(n2 + 255) / 256, 256, 0, stream>>>(W2, W2th, W2tl, HDIM, HDIM, HDIM);
    }
    dim3 g1(NROWS / 128, HDIM / 128);
    k_mfma_gemm<KP1, true><<<g1, 256, 0, stream>>>(Ah, Al, W1th, W1tl, b1,
                                                   h1h, h1l, nullptr, HDIM);
    dim3 g2(NROWS / 128, HDIM / 128);
    k_mfma_gemm<HDIM, false><<<g2, 256, 0, stream>>>(h1h, h1l, W2th, W2tl, b2,
                                                     nullptr, nullptr, h2, HDIM);
    int n3 = NROWS * NOUT;
    k_gemm3<<<(n3 + 255) / 256, 256, 0, stream>>>(h2, W3, b3, out);
}